// Round 2
// baseline (183.104 us; speedup 1.0000x reference)
//
#include <hip/hip_runtime.h>
#include <math.h>

// Single-kernel PBC neighbor-list distances + per-cutoff masks.
//
// Output layout (float32): [ d2[P] | mask0[P] | mask1[P] ... ]
//   P  = Pc + S*n*n,  Pc = n*(n-1)/2
//   p < Pc               : in-cell triu pair, row-major (i<j)
//   p = Pc + s*n*n+i*n+j : shifted-image pair (s,i,j)
//
// Grid layout (n%4==0 fast path):  grid = (max(n, triuBlocks), S+1), 256 thr.
//   blockIdx.y <  S : shifted plane. s = blockIdx.y, i = blockIdx.x,
//                     thread t owns j0 = 4t  (250 of 256 threads active at
//                     n=1000). NO integer division anywhere; shifts/cell/
//                     pos[i] addressing is block-uniform -> s_load'd.
//   blockIdx.y == S : triu plane, chunk = blockIdx.x*256+t, p0 = 4*chunk,
//                     per-element sqrt-guess + correction decode (3.7% of
//                     elements only).
//
// All 16B stores are aligned (Pc%4==0, n%4==0) and NONTEMPORAL via a native
// clang ext_vector (HIP float4 is a class -> rejected by the builtin):
// output (162 MB) is write-once and exceeds L2 (32 MB) -- don't pollute.
//
// Distance math in f64: matches the f64 validator at the mask boundary
// (d2 < cutoff^2); f64 cost is a few us, kernel should be store-bound.

typedef float f32x4 __attribute__((ext_vector_type(4)));

__device__ __forceinline__ void nt_store4(float* p, float a, float b, float c, float d)
{
    f32x4 v = {a, b, c, d};
    __builtin_nontemporal_store(v, (f32x4*)p);
}

__global__ void __launch_bounds__(256) nbr_kernel_grid(
    const float* __restrict__ pos,
    const float* __restrict__ cell,
    const float* __restrict__ shifts,
    const float* __restrict__ cutoffs,
    int ncut, int n, int S,
    float* __restrict__ out, long long P, long long Pc)
{
    double cut2[4];
#pragma unroll
    for (int c = 0; c < 4; ++c)
        if (c < ncut) { double cv = (double)cutoffs[c]; cut2[c] = cv * cv; }

    float d2f[4];
    float mf[4][4];

    if ((int)blockIdx.y < S) {
        // ---- shifted-image plane: (s,i) direct from blockIdx ----
        int s = (int)blockIdx.y;
        int i = (int)blockIdx.x;
        if (i >= n) return;                       // grid.x may exceed n
        int j0 = (int)threadIdx.x << 2;
        if (j0 >= n) return;                      // 250/256 active at n=1000

        // Block-uniform shift vector + pos[i] (compiler scalarizes loads).
        double s0 = (double)shifts[3*s+0], s1 = (double)shifts[3*s+1], s2 = (double)shifts[3*s+2];
        double sv0 = s0 * (double)cell[0] + s1 * (double)cell[3] + s2 * (double)cell[6];
        double sv1 = s0 * (double)cell[1] + s1 * (double)cell[4] + s2 * (double)cell[7];
        double sv2 = s0 * (double)cell[2] + s1 * (double)cell[5] + s2 * (double)cell[8];

        double pix = (double)pos[3*i+0];
        double piy = (double)pos[3*i+1];
        double piz = (double)pos[3*i+2];

        // 4 consecutive atoms j0..j0+3 = 12 floats, 48B-aligned (j0%4==0)
        const float4* pj = (const float4*)(pos + 3 * j0);
        float4 a = pj[0], b = pj[1], c4 = pj[2];
        float jx[4] = {a.x, a.w, b.z, c4.y};
        float jy[4] = {a.y, b.x, b.w, c4.z};
        float jz[4] = {a.z, b.y, c4.x, c4.w};

#pragma unroll
        for (int k = 0; k < 4; ++k) {
            double dx = (pix - (double)jx[k]) + sv0;
            double dy = (piy - (double)jy[k]) + sv1;
            double dz = (piz - (double)jz[k]) + sv2;
            double d2 = dx*dx + dy*dy + dz*dz;
            d2f[k] = (float)d2;
#pragma unroll
            for (int c = 0; c < 4; ++c)
                if (c < ncut) mf[c][k] = (d2 < cut2[c]) ? 1.0f : 0.0f;
        }

        long long base = Pc + ((long long)s * (long long)n + (long long)i) * (long long)n
                         + (long long)j0;
        nt_store4(out + base, d2f[0], d2f[1], d2f[2], d2f[3]);
#pragma unroll
        for (int c = 0; c < 4; ++c)
            if (c < ncut)
                nt_store4(out + (long long)(c + 1) * P + base,
                          mf[c][0], mf[c][1], mf[c][2], mf[c][3]);
    } else {
        // ---- in-cell triangular plane: decode (i,j) per element ----
        long long chunk = (long long)blockIdx.x * 256 + threadIdx.x;
        long long p0 = chunk << 2;
        if (p0 >= Pc) return;

        // Row i starts at A(i) = i*(2n-1-i)/2, holds j in (i, n).
        long long tn = 2LL * n - 1;
#pragma unroll
        for (int k = 0; k < 4; ++k) {
            long long p = p0 + k;
            double D = (double)(tn * tn) - 8.0 * (double)p;
            long long i = (long long)(((double)tn - sqrt(D)) * 0.5);
            if (i < 0) i = 0;
            if (i > n - 2) i = n - 2;
            while ((i + 1) * (tn - (i + 1)) / 2 <= p) ++i;   // A(i+1) <= p
            while (i * (tn - i) / 2 > p) --i;                // A(i)   >  p
            long long j = p - i * (tn - i) / 2 + i + 1;

            double dx = (double)pos[3*i+0] - (double)pos[3*j+0];
            double dy = (double)pos[3*i+1] - (double)pos[3*j+1];
            double dz = (double)pos[3*i+2] - (double)pos[3*j+2];
            double d2 = dx*dx + dy*dy + dz*dz;
            d2f[k] = (float)d2;
#pragma unroll
            for (int c = 0; c < 4; ++c)
                if (c < ncut) mf[c][k] = (d2 < cut2[c]) ? 1.0f : 0.0f;
        }

        nt_store4(out + p0, d2f[0], d2f[1], d2f[2], d2f[3]);
#pragma unroll
        for (int c = 0; c < 4; ++c)
            if (c < ncut)
                nt_store4(out + (long long)(c + 1) * P + p0,
                          mf[c][0], mf[c][1], mf[c][2], mf[c][3]);
    }
}

// Scalar fallback for n % 4 != 0 (not used at n=1000).
__global__ void __launch_bounds__(256) nbr_kernel_scalar(
    const float* __restrict__ pos,
    const float* __restrict__ cell,
    const float* __restrict__ shifts,
    const float* __restrict__ cutoffs,
    int ncut, int n,
    float* __restrict__ out, long long P, long long Pc)
{
    long long p = (long long)blockIdx.x * 256 + threadIdx.x;
    if (p >= P) return;

    double cut2[4];
    for (int c = 0; c < ncut; ++c) { double cv = (double)cutoffs[c]; cut2[c] = cv * cv; }

    double d2;
    if (p >= Pc) {
        long long q = p - Pc;
        unsigned long long nn = (unsigned long long)n * n;
        unsigned s = (unsigned)(q / nn);
        unsigned long long r = q - (unsigned long long)s * nn;
        unsigned i = (unsigned)(r / n);
        unsigned j = (unsigned)(r - (unsigned long long)i * n);
        double s0 = (double)shifts[3*s+0], s1 = (double)shifts[3*s+1], s2 = (double)shifts[3*s+2];
        double sv0 = s0*(double)cell[0] + s1*(double)cell[3] + s2*(double)cell[6];
        double sv1 = s0*(double)cell[1] + s1*(double)cell[4] + s2*(double)cell[7];
        double sv2 = s0*(double)cell[2] + s1*(double)cell[5] + s2*(double)cell[8];
        double dx = ((double)pos[3*i+0] - (double)pos[3*j+0]) + sv0;
        double dy = ((double)pos[3*i+1] - (double)pos[3*j+1]) + sv1;
        double dz = ((double)pos[3*i+2] - (double)pos[3*j+2]) + sv2;
        d2 = dx*dx + dy*dy + dz*dz;
    } else {
        long long tn = 2LL * n - 1;
        double D = (double)(tn * tn) - 8.0 * (double)p;
        long long i = (long long)(((double)tn - sqrt(D)) * 0.5);
        if (i < 0) i = 0;
        if (i > n - 2) i = n - 2;
        while ((i + 1) * (tn - (i + 1)) / 2 <= p) ++i;
        while (i * (tn - i) / 2 > p) --i;
        long long j = p - i * (tn - i) / 2 + i + 1;
        double dx = (double)pos[3*i+0] - (double)pos[3*j+0];
        double dy = (double)pos[3*i+1] - (double)pos[3*j+1];
        double dz = (double)pos[3*i+2] - (double)pos[3*j+2];
        d2 = dx*dx + dy*dy + dz*dz;
    }
    out[p] = (float)d2;
    for (int c = 0; c < ncut; ++c)
        out[(long long)(c + 1) * P + p] = (d2 < cut2[c]) ? 1.0f : 0.0f;
}

extern "C" void kernel_launch(void* const* d_in, const int* in_sizes, int n_in,
                              void* d_out, int out_size, void* d_ws, size_t ws_size,
                              hipStream_t stream)
{
    const float* pos     = (const float*)d_in[0];
    const float* cell    = (const float*)d_in[1];
    const float* shifts  = (const float*)d_in[2];
    const float* cutoffs = (const float*)d_in[3];
    int n    = in_sizes[0] / 3;   // 1000
    int S    = in_sizes[2] / 3;   // 13
    int ncut = in_sizes[3];       // 2

    long long Pc = (long long)n * (n - 1) / 2;          // 499500
    long long P  = Pc + (long long)S * n * n;           // 13499500
    float* out = (float*)d_out;

    if ((n & 3) == 0) {
        long long triuChunks = Pc >> 2;                          // 124,875
        int triuBlocks = (int)((triuChunks + 255) / 256);        // 488
        int gx = (n > triuBlocks) ? n : triuBlocks;              // 1000
        dim3 grid((unsigned)gx, (unsigned)(S + 1));
        nbr_kernel_grid<<<grid, 256, 0, stream>>>(pos, cell, shifts, cutoffs,
                                                  ncut, n, S, out, P, Pc);
    } else {
        int blocks = (int)((P + 255) / 256);
        nbr_kernel_scalar<<<blocks, 256, 0, stream>>>(pos, cell, shifts, cutoffs,
                                                      ncut, n, out, P, Pc);
    }
}